// Round 3
// baseline (1049.368 us; speedup 1.0000x reference)
//
#include <hip/hip_runtime.h>
#include <math.h>

// StyleLattice fused kernels (fp32, MI355X).
// Key fusion: mean_s(relu(grp@W1+b1) @ W2 + b2) == mean_s(relu(grp@W1+b1)) @ W2 + b2
// (no ReLU after W2) -> saves 34 GFLOP.
// No workspace use: static __device__ scratch (16B-aligned for float4 access);
// no atomics (deterministic partials).
// R2 resubmit: rounds 0-2 all failed in GPU-broker infra (no counters, no
// compile/validation signal) -- source unchanged after fresh correctness audit.

#define NB 65536           // batch
#define NELEM (65536 * 16) // B*16 output elems per tensor

__device__ __align__(16) float g_hbar[(size_t)NB * 128]; // mean_s relu(grp@W1+b1), [B,128]
__device__ __align__(16) float g_p2[512]; // per-block partials from K2: (kl_i_sum, vq_i_sum)
__device__ __align__(16) float g_p3[512]; // per-block partials from K3: (kl_g_sum, vq_g_sum)

// ---------------------------------------------------------------------------
// K1: group stage 1. Block = 64 (b,s)-rows x 128 cols. 256 threads, 8x4 tile.
// LDS: W1 32K + A 16K + misc ~= 51KB -> 3 blocks/CU.
// ---------------------------------------------------------------------------
__global__ __launch_bounds__(256, 3) void k1_group_stage1(
    const float* __restrict__ grp, const float* __restrict__ w1,
    const float* __restrict__ b1)
{
    __shared__ __align__(16) float Ws[64 * 128];
    __shared__ __align__(16) float As[64 * 64];
    __shared__ float b1s[128];
    __shared__ __align__(16) float hb[4 * 128];

    const int t = threadIdx.x;
    {
        const float4* ws4 = (const float4*)w1;
        float4* wd4 = (float4*)Ws;
#pragma unroll
        for (int i = 0; i < 8; i++) wd4[i * 256 + t] = ws4[i * 256 + t];
        const float4* as4 = (const float4*)(grp + (size_t)blockIdx.x * 4096);
        float4* ad4 = (float4*)As;
#pragma unroll
        for (int i = 0; i < 4; i++) ad4[i * 256 + t] = as4[i * 256 + t];
        if (t < 128) b1s[t] = b1[t];
    }
    __syncthreads();

    const int c4 = (t & 31) * 4;   // 4 output cols
    const int r0 = (t >> 5) * 8;   // 8 rows
    float acc[8][4];
#pragma unroll
    for (int r = 0; r < 8; r++) { acc[r][0] = 0.f; acc[r][1] = 0.f; acc[r][2] = 0.f; acc[r][3] = 0.f; }

    for (int k = 0; k < 64; k += 4) {
        float4 w0 = *(const float4*)&Ws[(k + 0) * 128 + c4];
        float4 w1v = *(const float4*)&Ws[(k + 1) * 128 + c4];
        float4 w2v = *(const float4*)&Ws[(k + 2) * 128 + c4];
        float4 w3v = *(const float4*)&Ws[(k + 3) * 128 + c4];
#pragma unroll
        for (int r = 0; r < 8; r++) {
            float4 a = *(const float4*)&As[(r0 + r) * 64 + k];
            acc[r][0] = fmaf(a.x, w0.x, acc[r][0]); acc[r][1] = fmaf(a.x, w0.y, acc[r][1]);
            acc[r][2] = fmaf(a.x, w0.z, acc[r][2]); acc[r][3] = fmaf(a.x, w0.w, acc[r][3]);
            acc[r][0] = fmaf(a.y, w1v.x, acc[r][0]); acc[r][1] = fmaf(a.y, w1v.y, acc[r][1]);
            acc[r][2] = fmaf(a.y, w1v.z, acc[r][2]); acc[r][3] = fmaf(a.y, w1v.w, acc[r][3]);
            acc[r][0] = fmaf(a.z, w2v.x, acc[r][0]); acc[r][1] = fmaf(a.z, w2v.y, acc[r][1]);
            acc[r][2] = fmaf(a.z, w2v.z, acc[r][2]); acc[r][3] = fmaf(a.z, w2v.w, acc[r][3]);
            acc[r][0] = fmaf(a.w, w3v.x, acc[r][0]); acc[r][1] = fmaf(a.w, w3v.y, acc[r][1]);
            acc[r][2] = fmaf(a.w, w3v.z, acc[r][2]); acc[r][3] = fmaf(a.w, w3v.w, acc[r][3]);
        }
    }

    // bias + relu + partial row-sum (8 rows, all within one s-group half)
    float rs[4];
#pragma unroll
    for (int cc = 0; cc < 4; cc++) {
        float s = 0.f;
#pragma unroll
        for (int r = 0; r < 8; r++) s += fmaxf(acc[r][cc] + b1s[c4 + cc], 0.f);
        rs[cc] = s;
    }
    const int g = r0 >> 4;                 // s-group (16 rows) within block
    const bool evenhalf = ((r0 >> 3) & 1) == 0;
    if (evenhalf) {
#pragma unroll
        for (int cc = 0; cc < 4; cc++) hb[g * 128 + c4 + cc] = rs[cc];
    }
    __syncthreads();
    if (!evenhalf) {
#pragma unroll
        for (int cc = 0; cc < 4; cc++) hb[g * 128 + c4 + cc] += rs[cc];
    }
    __syncthreads();
    if (t < 128) {
        const int gg = t >> 5, j4 = (t & 31) * 4;
        float4 v = *(const float4*)&hb[gg * 128 + j4];
        v.x *= 0.0625f; v.y *= 0.0625f; v.z *= 0.0625f; v.w *= 0.0625f;
        *(float4*)&g_hbar[((size_t)blockIdx.x * 4 + gg) * 128 + j4] = v;
    }
}

// ---------------------------------------------------------------------------
// K2: individual path, fully fused, thread-per-row. Weights are wave-uniform
// -> scalar/broadcast loads. All per-thread arrays statically indexed.
// ---------------------------------------------------------------------------
__global__ __launch_bounds__(256) void k2_individual(
    const float* __restrict__ ind, const float* __restrict__ eps,
    const float* __restrict__ w1, const float* __restrict__ b1,
    const float* __restrict__ w2, const float* __restrict__ b2,
    const float* __restrict__ muw, const float* __restrict__ mub,
    const float* __restrict__ lvw, const float* __restrict__ lvb,
    const float* __restrict__ cb, float* __restrict__ out)
{
    const int b = blockIdx.x * 256 + threadIdx.x;
    const float4* xr = (const float4*)(ind + (size_t)b * 64);

    // h1 = relu(x @ W1 + b1), in two 64-col passes
    float h1[128];
#pragma unroll
    for (int jc = 0; jc < 2; jc++) {
        float a[64];
        {
            const float* bp = b1 + jc * 64;
#pragma unroll
            for (int j = 0; j < 64; j++) a[j] = bp[j];
        }
#pragma unroll 1
        for (int kc = 0; kc < 4; kc++) {
            float xc[16];
#pragma unroll
            for (int i = 0; i < 4; i++) {
                float4 v = xr[kc * 4 + i];
                xc[i * 4 + 0] = v.x; xc[i * 4 + 1] = v.y; xc[i * 4 + 2] = v.z; xc[i * 4 + 3] = v.w;
            }
#pragma unroll
            for (int k = 0; k < 16; k++) {
                const float* wr = w1 + (kc * 16 + k) * 128 + jc * 64;
#pragma unroll
                for (int j = 0; j < 64; j++) a[j] = fmaf(xc[k], wr[j], a[j]);
            }
        }
#pragma unroll
        for (int j = 0; j < 64; j++) h1[jc * 64 + j] = fmaxf(a[j], 0.f);
    }

    // h2 = relu(h1 @ W2 + b2) in 32-col chunks, fused into mu/lv projection
    float mu[16], lv[16];
#pragma unroll
    for (int j = 0; j < 16; j++) { mu[j] = mub[j]; lv[j] = lvb[j]; }
#pragma unroll 1
    for (int c = 0; c < 4; c++) {
        float h2c[32];
        {
            const float* bp = b2 + c * 32;
#pragma unroll
            for (int j = 0; j < 32; j++) h2c[j] = bp[j];
        }
#pragma unroll
        for (int k = 0; k < 128; k++) {
            const float* wr = w2 + k * 128 + c * 32;
#pragma unroll
            for (int j = 0; j < 32; j++) h2c[j] = fmaf(h1[k], wr[j], h2c[j]);
        }
#pragma unroll
        for (int k = 0; k < 32; k++) {
            float h = fmaxf(h2c[k], 0.f);
            const float* mr = muw + (c * 32 + k) * 16;
            const float* lr = lvw + (c * 32 + k) * 16;
#pragma unroll
            for (int j = 0; j < 16; j++) {
                mu[j] = fmaf(h, mr[j], mu[j]);
                lv[j] = fmaf(h, lr[j], lv[j]);
            }
        }
    }

    // reparameterize + kl_i partial
    float e[16];
    {
        const float4* er = (const float4*)(eps + (size_t)b * 16);
#pragma unroll
        for (int i = 0; i < 4; i++) {
            float4 v = er[i];
            e[i * 4 + 0] = v.x; e[i * 4 + 1] = v.y; e[i * 4 + 2] = v.z; e[i * 4 + 3] = v.w;
        }
    }
    float z[16];
    float klp = 0.f;
#pragma unroll
    for (int j = 0; j < 16; j++) {
        float m = mu[j], l = lv[j];
        z[j] = fmaf(e[j], expf(0.5f * l), m);
        klp += 1.f + l - m * m - expf(l);
    }

    // VQ argmin over 64 codes (|cb|^2 - 2 z.cb; |z|^2 constant per row)
    float best = 3.4e38f; int bi = 0;
#pragma unroll 1
    for (int c = 0; c < 64; c++) {
        const float* cr = cb + c * 16;
        float dot = 0.f, nrm = 0.f;
#pragma unroll
        for (int j = 0; j < 16; j++) { float cv = cr[j]; dot = fmaf(z[j], cv, dot); nrm = fmaf(cv, cv, nrm); }
        float d = nrm - 2.f * dot;
        if (d < best) { best = d; bi = c; }
    }
    const float4* cq = (const float4*)(cb + bi * 16); // per-lane gather
    float vqp = 0.f;
    float zi[16];
#pragma unroll
    for (int i = 0; i < 4; i++) {
        float4 q = cq[i];
        float qq[4] = { q.x, q.y, q.z, q.w };
#pragma unroll
        for (int jj = 0; jj < 4; jj++) {
            int j = i * 4 + jj;
            float diff = qq[jj] - z[j];
            vqp += diff * diff;
            zi[j] = z[j] + diff; // straight-through value, same fp ops as reference
        }
    }

    // stores
    {
        float4* o_zi = (float4*)(out + (size_t)b * 16);
        float4* o_zc = (float4*)(out + (size_t)NELEM + (size_t)b * 16);
#pragma unroll
        for (int i = 0; i < 4; i++) {
            o_zi[i] = make_float4(zi[i * 4], zi[i * 4 + 1], zi[i * 4 + 2], zi[i * 4 + 3]);
            o_zc[i] = make_float4(z[i * 4], z[i * 4 + 1], z[i * 4 + 2], z[i * 4 + 3]);
        }
    }

    // deterministic block reduction of (klp, vqp)
#pragma unroll
    for (int m = 32; m >= 1; m >>= 1) { klp += __shfl_xor(klp, m); vqp += __shfl_xor(vqp, m); }
    __shared__ float red[4][2];
    const int wv = threadIdx.x >> 6, ln = threadIdx.x & 63;
    if (ln == 0) { red[wv][0] = klp; red[wv][1] = vqp; }
    __syncthreads();
    if (threadIdx.x == 0) {
        float a = 0.f, c = 0.f;
#pragma unroll
        for (int w = 0; w < 4; w++) { a += red[w][0]; c += red[w][1]; }
        g_p2[blockIdx.x * 2 + 0] = a;
        g_p2[blockIdx.x * 2 + 1] = c;
    }
}

// ---------------------------------------------------------------------------
// K3: group stage 2: hG = hbar @ W2 + b2 + ctx @ Wc + bc (no relu);
// mu_g/lv_g, prior, sample, VQ(32 codes), kl_g.
// ---------------------------------------------------------------------------
__global__ __launch_bounds__(256) void k3_group_stage2(
    const float* __restrict__ ctx, const float* __restrict__ eps,
    const float* __restrict__ w2, const float* __restrict__ b2,
    const float* __restrict__ cw, const float* __restrict__ cbias,
    const float* __restrict__ muw, const float* __restrict__ mub,
    const float* __restrict__ lvw, const float* __restrict__ lvb,
    const float* __restrict__ cbg,
    const float* __restrict__ pmw, const float* __restrict__ pmb,
    const float* __restrict__ plw, const float* __restrict__ plb,
    float* __restrict__ out)
{
    const int b = blockIdx.x * 256 + threadIdx.x;
    const float4* hr = (const float4*)(g_hbar + (size_t)b * 128);
    const float4* cr4 = (const float4*)(ctx + (size_t)b * 32);

    float hG[128];
#pragma unroll
    for (int jc = 0; jc < 2; jc++) {
        float a[64];
        {
            const float* bp = b2 + jc * 64;
#pragma unroll
            for (int j = 0; j < 64; j++) a[j] = bp[j];
        }
#pragma unroll 1
        for (int kc = 0; kc < 8; kc++) {
            float xc[16];
#pragma unroll
            for (int i = 0; i < 4; i++) {
                float4 v = hr[kc * 4 + i];
                xc[i * 4 + 0] = v.x; xc[i * 4 + 1] = v.y; xc[i * 4 + 2] = v.z; xc[i * 4 + 3] = v.w;
            }
#pragma unroll
            for (int k = 0; k < 16; k++) {
                const float* wr = w2 + (kc * 16 + k) * 128 + jc * 64;
#pragma unroll
                for (int j = 0; j < 64; j++) a[j] = fmaf(xc[k], wr[j], a[j]);
            }
        }
#pragma unroll 1
        for (int kc = 0; kc < 2; kc++) {
            float xc[16];
#pragma unroll
            for (int i = 0; i < 4; i++) {
                float4 v = cr4[kc * 4 + i];
                xc[i * 4 + 0] = v.x; xc[i * 4 + 1] = v.y; xc[i * 4 + 2] = v.z; xc[i * 4 + 3] = v.w;
            }
#pragma unroll
            for (int k = 0; k < 16; k++) {
                const float* wr = cw + (kc * 16 + k) * 128 + jc * 64;
#pragma unroll
                for (int j = 0; j < 64; j++) a[j] = fmaf(xc[k], wr[j], a[j]);
            }
        }
#pragma unroll
        for (int j = 0; j < 64; j++) hG[jc * 64 + j] = a[j] + cbias[jc * 64 + j];
    }

    // mu_g / lv_g
    float mu[16], lv[16];
#pragma unroll
    for (int j = 0; j < 16; j++) { mu[j] = mub[j]; lv[j] = lvb[j]; }
#pragma unroll
    for (int k = 0; k < 128; k++) {
        float h = hG[k];
        const float* mr = muw + k * 16;
        const float* lr = lvw + k * 16;
#pragma unroll
        for (int j = 0; j < 16; j++) {
            mu[j] = fmaf(h, mr[j], mu[j]);
            lv[j] = fmaf(h, lr[j], lv[j]);
        }
    }

    // prior from ctx
    float cx[32];
#pragma unroll
    for (int i = 0; i < 8; i++) {
        float4 v = cr4[i];
        cx[i * 4 + 0] = v.x; cx[i * 4 + 1] = v.y; cx[i * 4 + 2] = v.z; cx[i * 4 + 3] = v.w;
    }
    float pmu[16], plv[16];
#pragma unroll
    for (int j = 0; j < 16; j++) { pmu[j] = pmb[j]; plv[j] = plb[j]; }
#pragma unroll
    for (int k = 0; k < 32; k++) {
        const float* mr = pmw + k * 16;
        const float* lr = plw + k * 16;
#pragma unroll
        for (int j = 0; j < 16; j++) {
            pmu[j] = fmaf(cx[k], mr[j], pmu[j]);
            plv[j] = fmaf(cx[k], lr[j], plv[j]);
        }
    }

    // sample + kl_g partial
    float e[16];
    {
        const float4* er = (const float4*)(eps + (size_t)b * 16);
#pragma unroll
        for (int i = 0; i < 4; i++) {
            float4 v = er[i];
            e[i * 4 + 0] = v.x; e[i * 4 + 1] = v.y; e[i * 4 + 2] = v.z; e[i * 4 + 3] = v.w;
        }
    }
    float z[16];
    float klp = 0.f;
#pragma unroll
    for (int j = 0; j < 16; j++) {
        float m = mu[j], l = lv[j];
        z[j] = fmaf(e[j], expf(0.5f * l), m);
        float dm = m - pmu[j];
        klp += plv[j] - l + (expf(l) + dm * dm) / expf(plv[j]) - 1.f;
    }

    // VQ over 32 codes
    float best = 3.4e38f; int bi = 0;
#pragma unroll 1
    for (int c = 0; c < 32; c++) {
        const float* cr = cbg + c * 16;
        float dot = 0.f, nrm = 0.f;
#pragma unroll
        for (int j = 0; j < 16; j++) { float cv = cr[j]; dot = fmaf(z[j], cv, dot); nrm = fmaf(cv, cv, nrm); }
        float d = nrm - 2.f * dot;
        if (d < best) { best = d; bi = c; }
    }
    const float4* cq = (const float4*)(cbg + bi * 16);
    float vqp = 0.f;
    float zg[16];
#pragma unroll
    for (int i = 0; i < 4; i++) {
        float4 q = cq[i];
        float qq[4] = { q.x, q.y, q.z, q.w };
#pragma unroll
        for (int jj = 0; jj < 4; jj++) {
            int j = i * 4 + jj;
            float diff = qq[jj] - z[j];
            vqp += diff * diff;
            zg[j] = z[j] + diff;
        }
    }

    {
        float4* o_zg = (float4*)(out + (size_t)2 * NELEM + (size_t)b * 16);
        float4* o_zc = (float4*)(out + (size_t)3 * NELEM + (size_t)b * 16);
#pragma unroll
        for (int i = 0; i < 4; i++) {
            o_zg[i] = make_float4(zg[i * 4], zg[i * 4 + 1], zg[i * 4 + 2], zg[i * 4 + 3]);
            o_zc[i] = make_float4(z[i * 4], z[i * 4 + 1], z[i * 4 + 2], z[i * 4 + 3]);
        }
    }

#pragma unroll
    for (int m = 32; m >= 1; m >>= 1) { klp += __shfl_xor(klp, m); vqp += __shfl_xor(vqp, m); }
    __shared__ float red[4][2];
    const int wv = threadIdx.x >> 6, ln = threadIdx.x & 63;
    if (ln == 0) { red[wv][0] = klp; red[wv][1] = vqp; }
    __syncthreads();
    if (threadIdx.x == 0) {
        float a = 0.f, c = 0.f;
#pragma unroll
        for (int w = 0; w < 4; w++) { a += red[w][0]; c += red[w][1]; }
        g_p3[blockIdx.x * 2 + 0] = a;
        g_p3[blockIdx.x * 2 + 1] = c;
    }
}

// ---------------------------------------------------------------------------
// K4: final deterministic reduction -> loss_style, kl_i, kl_g
// ---------------------------------------------------------------------------
__global__ __launch_bounds__(256) void k4_finalize(float* __restrict__ out)
{
    const int t = threadIdx.x;
    float kli = g_p2[t * 2 + 0], vqi = g_p2[t * 2 + 1];
    float klg = g_p3[t * 2 + 0], vqg = g_p3[t * 2 + 1];
#pragma unroll
    for (int m = 32; m >= 1; m >>= 1) {
        kli += __shfl_xor(kli, m); vqi += __shfl_xor(vqi, m);
        klg += __shfl_xor(klg, m); vqg += __shfl_xor(vqg, m);
    }
    __shared__ float red[4][4];
    const int wv = t >> 6, ln = t & 63;
    if (ln == 0) { red[wv][0] = kli; red[wv][1] = vqi; red[wv][2] = klg; red[wv][3] = vqg; }
    __syncthreads();
    if (t == 0) {
        float a = 0.f, bq = 0.f, c = 0.f, d = 0.f;
#pragma unroll
        for (int w = 0; w < 4; w++) { a += red[w][0]; bq += red[w][1]; c += red[w][2]; d += red[w][3]; }
        const float invN = 1.f / (float)NELEM;
        float kl_i = -0.5f * a * invN;
        float vq_i = 0.5f * bq * invN;   // 0.25 * (commit + code) = 0.5 * mse
        float kl_g = 0.5f * c * invN;
        float vq_g = 0.5f * d * invN;
        out[(size_t)4 * NELEM + 0] = 2.0f * (kl_i + kl_g) + vq_i + vq_g;
        out[(size_t)4 * NELEM + 1] = kl_i;
        out[(size_t)4 * NELEM + 2] = kl_g;
    }
}

extern "C" void kernel_launch(void* const* d_in, const int* in_sizes, int n_in,
                              void* d_out, int out_size, void* d_ws, size_t ws_size,
                              hipStream_t stream)
{
    (void)in_sizes; (void)n_in; (void)out_size; (void)d_ws; (void)ws_size;
    const float* ind     = (const float*)d_in[0];
    const float* grp     = (const float*)d_in[1];
    const float* ctx     = (const float*)d_in[2];
    const float* eps_i   = (const float*)d_in[3];
    const float* eps_g   = (const float*)d_in[4];
    const float* ei_w1   = (const float*)d_in[5];
    const float* ei_b1   = (const float*)d_in[6];
    const float* ei_w2   = (const float*)d_in[7];
    const float* ei_b2   = (const float*)d_in[8];
    const float* ei_mu_w = (const float*)d_in[9];
    const float* ei_mu_b = (const float*)d_in[10];
    const float* ei_lv_w = (const float*)d_in[11];
    const float* ei_lv_b = (const float*)d_in[12];
    const float* cb_i    = (const float*)d_in[13];
    const float* eg_w1   = (const float*)d_in[14];
    const float* eg_b1   = (const float*)d_in[15];
    const float* eg_w2   = (const float*)d_in[16];
    const float* eg_b2   = (const float*)d_in[17];
    const float* eg_ctxw = (const float*)d_in[18];
    const float* eg_ctxb = (const float*)d_in[19];
    const float* eg_mu_w = (const float*)d_in[20];
    const float* eg_mu_b = (const float*)d_in[21];
    const float* eg_lv_w = (const float*)d_in[22];
    const float* eg_lv_b = (const float*)d_in[23];
    const float* cb_g    = (const float*)d_in[24];
    const float* pr_mu_w = (const float*)d_in[25];
    const float* pr_mu_b = (const float*)d_in[26];
    const float* pr_lv_w = (const float*)d_in[27];
    const float* pr_lv_b = (const float*)d_in[28];
    float* out = (float*)d_out;

    k1_group_stage1<<<16384, 256, 0, stream>>>(grp, eg_w1, eg_b1);
    k2_individual<<<256, 256, 0, stream>>>(ind, eps_i, ei_w1, ei_b1, ei_w2, ei_b2,
                                           ei_mu_w, ei_mu_b, ei_lv_w, ei_lv_b, cb_i, out);
    k3_group_stage2<<<256, 256, 0, stream>>>(ctx, eps_g, eg_w2, eg_b2, eg_ctxw, eg_ctxb,
                                             eg_mu_w, eg_mu_b, eg_lv_w, eg_lv_b, cb_g,
                                             pr_mu_w, pr_mu_b, pr_lv_w, pr_lv_b, out);
    k4_finalize<<<1, 256, 0, stream>>>(out);
}

// Round 4
// 762.809 us; speedup vs baseline: 1.3757x; 1.3757x over previous
//
#include <hip/hip_runtime.h>
#include <math.h>

// StyleLattice fused kernels (fp32, MI355X).
// R3 evidence: k2 thread-per-row = 308us, VALUBusy 14%, 1 wave/SIMD -> serial
// s_load latency exposed. K2/K3 rewritten as LDS-tiled (64 rows/block, 1024
// blocks, vector weight loads from L2, head phase on wave0 with XOR-swizzled
// LDS rows). K1/K4 unchanged (K1 counters land next round).
// Key fusion retained: mean_s(relu(grp@W1+b1) @ W2 + b2) == mean_s(relu(.)) @ W2 + b2.

#define NB 65536           // batch
#define NELEM (65536 * 16) // B*16 output elems per tensor

__device__ __align__(16) float g_hbar[(size_t)NB * 128]; // mean_s relu(grp@W1+b1), [B,128]
__device__ __align__(16) float g_p2[2048]; // per-block partials K2: (kl_i_sum, vq_i_sum) x1024
__device__ __align__(16) float g_p3[2048]; // per-block partials K3: (kl_g_sum, vq_g_sum) x1024

// ---------------------------------------------------------------------------
// K1: group stage 1 (unchanged this round). Block = 64 (b,s)-rows x 128 cols.
// ---------------------------------------------------------------------------
__global__ __launch_bounds__(256, 3) void k1_group_stage1(
    const float* __restrict__ grp, const float* __restrict__ w1,
    const float* __restrict__ b1)
{
    __shared__ __align__(16) float Ws[64 * 128];
    __shared__ __align__(16) float As[64 * 64];
    __shared__ float b1s[128];
    __shared__ __align__(16) float hb[4 * 128];

    const int t = threadIdx.x;
    {
        const float4* ws4 = (const float4*)w1;
        float4* wd4 = (float4*)Ws;
#pragma unroll
        for (int i = 0; i < 8; i++) wd4[i * 256 + t] = ws4[i * 256 + t];
        const float4* as4 = (const float4*)(grp + (size_t)blockIdx.x * 4096);
        float4* ad4 = (float4*)As;
#pragma unroll
        for (int i = 0; i < 4; i++) ad4[i * 256 + t] = as4[i * 256 + t];
        if (t < 128) b1s[t] = b1[t];
    }
    __syncthreads();

    const int c4 = (t & 31) * 4;   // 4 output cols
    const int r0 = (t >> 5) * 8;   // 8 rows
    float acc[8][4];
#pragma unroll
    for (int r = 0; r < 8; r++) { acc[r][0] = 0.f; acc[r][1] = 0.f; acc[r][2] = 0.f; acc[r][3] = 0.f; }

    for (int k = 0; k < 64; k += 4) {
        float4 w0 = *(const float4*)&Ws[(k + 0) * 128 + c4];
        float4 w1v = *(const float4*)&Ws[(k + 1) * 128 + c4];
        float4 w2v = *(const float4*)&Ws[(k + 2) * 128 + c4];
        float4 w3v = *(const float4*)&Ws[(k + 3) * 128 + c4];
#pragma unroll
        for (int r = 0; r < 8; r++) {
            float4 a = *(const float4*)&As[(r0 + r) * 64 + k];
            acc[r][0] = fmaf(a.x, w0.x, acc[r][0]); acc[r][1] = fmaf(a.x, w0.y, acc[r][1]);
            acc[r][2] = fmaf(a.x, w0.z, acc[r][2]); acc[r][3] = fmaf(a.x, w0.w, acc[r][3]);
            acc[r][0] = fmaf(a.y, w1v.x, acc[r][0]); acc[r][1] = fmaf(a.y, w1v.y, acc[r][1]);
            acc[r][2] = fmaf(a.y, w1v.z, acc[r][2]); acc[r][3] = fmaf(a.y, w1v.w, acc[r][3]);
            acc[r][0] = fmaf(a.z, w2v.x, acc[r][0]); acc[r][1] = fmaf(a.z, w2v.y, acc[r][1]);
            acc[r][2] = fmaf(a.z, w2v.z, acc[r][2]); acc[r][3] = fmaf(a.z, w2v.w, acc[r][3]);
            acc[r][0] = fmaf(a.w, w3v.x, acc[r][0]); acc[r][1] = fmaf(a.w, w3v.y, acc[r][1]);
            acc[r][2] = fmaf(a.w, w3v.z, acc[r][2]); acc[r][3] = fmaf(a.w, w3v.w, acc[r][3]);
        }
    }

    float rs[4];
#pragma unroll
    for (int cc = 0; cc < 4; cc++) {
        float s = 0.f;
#pragma unroll
        for (int r = 0; r < 8; r++) s += fmaxf(acc[r][cc] + b1s[c4 + cc], 0.f);
        rs[cc] = s;
    }
    const int g = r0 >> 4;
    const bool evenhalf = ((r0 >> 3) & 1) == 0;
    if (evenhalf) {
#pragma unroll
        for (int cc = 0; cc < 4; cc++) hb[g * 128 + c4 + cc] = rs[cc];
    }
    __syncthreads();
    if (!evenhalf) {
#pragma unroll
        for (int cc = 0; cc < 4; cc++) hb[g * 128 + c4 + cc] += rs[cc];
    }
    __syncthreads();
    if (t < 128) {
        const int gg = t >> 5, j4 = (t & 31) * 4;
        float4 v = *(const float4*)&hb[gg * 128 + j4];
        v.x *= 0.0625f; v.y *= 0.0625f; v.z *= 0.0625f; v.w *= 0.0625f;
        *(float4*)&g_hbar[((size_t)blockIdx.x * 4 + gg) * 128 + j4] = v;
    }
}

// ---------------------------------------------------------------------------
// K2 (tiled): 64 rows/block, 1024 blocks. LDS: X 16K + H1 32K + H2 32K = 80K
// -> 2 blocks/CU, 8 waves/CU. GEMMs read weights as coalesced per-lane vector
// loads (L2-resident, pipelined). Heads: wave 0, thread-per-row, H2 rows read
// via XOR-swizzle (col ^= (row&7)<<2) to break the D=128 bank conflict.
// ---------------------------------------------------------------------------
__global__ __launch_bounds__(256, 2) void k2_individual(
    const float* __restrict__ ind, const float* __restrict__ eps,
    const float* __restrict__ w1, const float* __restrict__ b1,
    const float* __restrict__ w2, const float* __restrict__ b2,
    const float* __restrict__ muw, const float* __restrict__ mub,
    const float* __restrict__ lvw, const float* __restrict__ lvb,
    const float* __restrict__ cb, float* __restrict__ out)
{
    __shared__ __align__(16) float Xs[64 * 64];
    __shared__ __align__(16) float H1[64 * 128];
    __shared__ __align__(16) float H2[64 * 128];

    const int t = threadIdx.x;
    const int R0 = blockIdx.x * 64;

    {   // stage X tile (16 KB contiguous)
        const float4* src = (const float4*)(ind + (size_t)R0 * 64);
        float4* dst = (float4*)Xs;
#pragma unroll
        for (int i = 0; i < 4; i++) dst[i * 256 + t] = src[i * 256 + t];
    }
    __syncthreads();

    const int c4 = (t & 31) * 4;
    const int r0 = (t >> 5) * 8;
    float acc[8][4];

    // ---- layer 1: H1 = relu(X @ W1 + b1) ----
    {
        float4 bv = *(const float4*)(b1 + c4);
#pragma unroll
        for (int r = 0; r < 8; r++) { acc[r][0] = bv.x; acc[r][1] = bv.y; acc[r][2] = bv.z; acc[r][3] = bv.w; }
    }
    for (int k = 0; k < 64; k += 4) {
        float4 w0 = *(const float4*)(w1 + (size_t)(k + 0) * 128 + c4);
        float4 wv1 = *(const float4*)(w1 + (size_t)(k + 1) * 128 + c4);
        float4 wv2 = *(const float4*)(w1 + (size_t)(k + 2) * 128 + c4);
        float4 wv3 = *(const float4*)(w1 + (size_t)(k + 3) * 128 + c4);
#pragma unroll
        for (int r = 0; r < 8; r++) {
            float4 a = *(const float4*)&Xs[(r0 + r) * 64 + k];
            acc[r][0] = fmaf(a.x, w0.x, acc[r][0]); acc[r][1] = fmaf(a.x, w0.y, acc[r][1]);
            acc[r][2] = fmaf(a.x, w0.z, acc[r][2]); acc[r][3] = fmaf(a.x, w0.w, acc[r][3]);
            acc[r][0] = fmaf(a.y, wv1.x, acc[r][0]); acc[r][1] = fmaf(a.y, wv1.y, acc[r][1]);
            acc[r][2] = fmaf(a.y, wv1.z, acc[r][2]); acc[r][3] = fmaf(a.y, wv1.w, acc[r][3]);
            acc[r][0] = fmaf(a.z, wv2.x, acc[r][0]); acc[r][1] = fmaf(a.z, wv2.y, acc[r][1]);
            acc[r][2] = fmaf(a.z, wv2.z, acc[r][2]); acc[r][3] = fmaf(a.z, wv2.w, acc[r][3]);
            acc[r][0] = fmaf(a.w, wv3.x, acc[r][0]); acc[r][1] = fmaf(a.w, wv3.y, acc[r][1]);
            acc[r][2] = fmaf(a.w, wv3.z, acc[r][2]); acc[r][3] = fmaf(a.w, wv3.w, acc[r][3]);
        }
    }
#pragma unroll
    for (int r = 0; r < 8; r++) {
        float4 v = make_float4(fmaxf(acc[r][0], 0.f), fmaxf(acc[r][1], 0.f),
                               fmaxf(acc[r][2], 0.f), fmaxf(acc[r][3], 0.f));
        *(float4*)&H1[(r0 + r) * 128 + c4] = v;
    }
    __syncthreads();

    // ---- layer 2: H2 = relu(H1 @ W2 + b2), stored XOR-swizzled ----
    {
        float4 bv = *(const float4*)(b2 + c4);
#pragma unroll
        for (int r = 0; r < 8; r++) { acc[r][0] = bv.x; acc[r][1] = bv.y; acc[r][2] = bv.z; acc[r][3] = bv.w; }
    }
    for (int k = 0; k < 128; k += 4) {
        float4 w0 = *(const float4*)(w2 + (size_t)(k + 0) * 128 + c4);
        float4 wv1 = *(const float4*)(w2 + (size_t)(k + 1) * 128 + c4);
        float4 wv2 = *(const float4*)(w2 + (size_t)(k + 2) * 128 + c4);
        float4 wv3 = *(const float4*)(w2 + (size_t)(k + 3) * 128 + c4);
#pragma unroll
        for (int r = 0; r < 8; r++) {
            float4 a = *(const float4*)&H1[(r0 + r) * 128 + k];
            acc[r][0] = fmaf(a.x, w0.x, acc[r][0]); acc[r][1] = fmaf(a.x, w0.y, acc[r][1]);
            acc[r][2] = fmaf(a.x, w0.z, acc[r][2]); acc[r][3] = fmaf(a.x, w0.w, acc[r][3]);
            acc[r][0] = fmaf(a.y, wv1.x, acc[r][0]); acc[r][1] = fmaf(a.y, wv1.y, acc[r][1]);
            acc[r][2] = fmaf(a.y, wv1.z, acc[r][2]); acc[r][3] = fmaf(a.y, wv1.w, acc[r][3]);
            acc[r][0] = fmaf(a.z, wv2.x, acc[r][0]); acc[r][1] = fmaf(a.z, wv2.y, acc[r][1]);
            acc[r][2] = fmaf(a.z, wv2.z, acc[r][2]); acc[r][3] = fmaf(a.z, wv2.w, acc[r][3]);
            acc[r][0] = fmaf(a.w, wv3.x, acc[r][0]); acc[r][1] = fmaf(a.w, wv3.y, acc[r][1]);
            acc[r][2] = fmaf(a.w, wv3.z, acc[r][2]); acc[r][3] = fmaf(a.w, wv3.w, acc[r][3]);
        }
    }
#pragma unroll
    for (int r = 0; r < 8; r++) {
        const int row = r0 + r;
        const int sc = c4 ^ ((row & 7) << 2);  // 16B-slot swizzle
        float4 v = make_float4(fmaxf(acc[r][0], 0.f), fmaxf(acc[r][1], 0.f),
                               fmaxf(acc[r][2], 0.f), fmaxf(acc[r][3], 0.f));
        *(float4*)&H2[row * 128 + sc] = v;
    }
    __syncthreads();

    // ---- heads: wave 0, one thread per row ----
    if (t < 64) {
        const int row = R0 + t;
        const int sw = (t & 7) << 2;

        float mu[16], lv[16];
#pragma unroll
        for (int j = 0; j < 16; j++) { mu[j] = mub[j]; lv[j] = lvb[j]; }
        for (int kq = 0; kq < 32; kq++) {
            float4 h = *(const float4*)&H2[t * 128 + ((kq * 4) ^ sw)];
            float hh[4] = { h.x, h.y, h.z, h.w };
#pragma unroll
            for (int u = 0; u < 4; u++) {
                const int k = kq * 4 + u;
                const float* mr = muw + k * 16;
                const float* lr = lvw + k * 16;
#pragma unroll
                for (int j = 0; j < 16; j++) {
                    mu[j] = fmaf(hh[u], mr[j], mu[j]);
                    lv[j] = fmaf(hh[u], lr[j], lv[j]);
                }
            }
        }

        float e[16];
        {
            const float4* er = (const float4*)(eps + (size_t)row * 16);
#pragma unroll
            for (int i = 0; i < 4; i++) {
                float4 v = er[i];
                e[i * 4 + 0] = v.x; e[i * 4 + 1] = v.y; e[i * 4 + 2] = v.z; e[i * 4 + 3] = v.w;
            }
        }
        float z[16];
        float klp = 0.f;
#pragma unroll
        for (int j = 0; j < 16; j++) {
            float m = mu[j], l = lv[j];
            z[j] = fmaf(e[j], expf(0.5f * l), m);
            klp += 1.f + l - m * m - expf(l);
        }

        float best = 3.4e38f; int bi = 0;
        for (int c = 0; c < 64; c++) {
            const float* cr = cb + c * 16;
            float dot = 0.f, nrm = 0.f;
#pragma unroll
            for (int j = 0; j < 16; j++) { float cv = cr[j]; dot = fmaf(z[j], cv, dot); nrm = fmaf(cv, cv, nrm); }
            float d = nrm - 2.f * dot;
            if (d < best) { best = d; bi = c; }
        }
        const float4* cq = (const float4*)(cb + bi * 16);
        float vqp = 0.f;
        float zi[16];
#pragma unroll
        for (int i = 0; i < 4; i++) {
            float4 q = cq[i];
            float qq[4] = { q.x, q.y, q.z, q.w };
#pragma unroll
            for (int jj = 0; jj < 4; jj++) {
                int j = i * 4 + jj;
                float diff = qq[jj] - z[j];
                vqp += diff * diff;
                zi[j] = z[j] + diff;
            }
        }

        {
            float4* o_zi = (float4*)(out + (size_t)row * 16);
            float4* o_zc = (float4*)(out + (size_t)NELEM + (size_t)row * 16);
#pragma unroll
            for (int i = 0; i < 4; i++) {
                o_zi[i] = make_float4(zi[i * 4], zi[i * 4 + 1], zi[i * 4 + 2], zi[i * 4 + 3]);
                o_zc[i] = make_float4(z[i * 4], z[i * 4 + 1], z[i * 4 + 2], z[i * 4 + 3]);
            }
        }

#pragma unroll
        for (int m = 32; m >= 1; m >>= 1) { klp += __shfl_xor(klp, m); vqp += __shfl_xor(vqp, m); }
        if (t == 0) {
            g_p2[blockIdx.x * 2 + 0] = klp;
            g_p2[blockIdx.x * 2 + 1] = vqp;
        }
    }
}

// ---------------------------------------------------------------------------
// K3 (tiled): 64 rows/block, 1024 blocks. LDS: Hbar 32K + Cs 8K + HG 32K = 72K
// -> 2 blocks/CU. hG = hbar@W2 + b2 + ctx@Wc + cb (no relu), then heads on
// wave 0 (ctx row re-read from global to avoid the LDS column conflict).
// ---------------------------------------------------------------------------
__global__ __launch_bounds__(256, 2) void k3_group_stage2(
    const float* __restrict__ ctx, const float* __restrict__ eps,
    const float* __restrict__ w2, const float* __restrict__ b2,
    const float* __restrict__ cw, const float* __restrict__ cbias,
    const float* __restrict__ muw, const float* __restrict__ mub,
    const float* __restrict__ lvw, const float* __restrict__ lvb,
    const float* __restrict__ cbg,
    const float* __restrict__ pmw, const float* __restrict__ pmb,
    const float* __restrict__ plw, const float* __restrict__ plb,
    float* __restrict__ out)
{
    __shared__ __align__(16) float Hs[64 * 128];
    __shared__ __align__(16) float Cs[64 * 32];
    __shared__ __align__(16) float HG[64 * 128];

    const int t = threadIdx.x;
    const int R0 = blockIdx.x * 64;

    {
        const float4* src = (const float4*)(g_hbar + (size_t)R0 * 128);
        float4* dst = (float4*)Hs;
#pragma unroll
        for (int i = 0; i < 8; i++) dst[i * 256 + t] = src[i * 256 + t];
        const float4* cs = (const float4*)(ctx + (size_t)R0 * 32);
        float4* cd = (float4*)Cs;
#pragma unroll
        for (int i = 0; i < 2; i++) cd[i * 256 + t] = cs[i * 256 + t];
    }
    __syncthreads();

    const int c4 = (t & 31) * 4;
    const int r0 = (t >> 5) * 8;
    float acc[8][4];
    {
        float4 bv = *(const float4*)(b2 + c4);
        float4 cv = *(const float4*)(cbias + c4);
        bv.x += cv.x; bv.y += cv.y; bv.z += cv.z; bv.w += cv.w;
#pragma unroll
        for (int r = 0; r < 8; r++) { acc[r][0] = bv.x; acc[r][1] = bv.y; acc[r][2] = bv.z; acc[r][3] = bv.w; }
    }
    for (int k = 0; k < 128; k += 4) {
        float4 w0 = *(const float4*)(w2 + (size_t)(k + 0) * 128 + c4);
        float4 wv1 = *(const float4*)(w2 + (size_t)(k + 1) * 128 + c4);
        float4 wv2 = *(const float4*)(w2 + (size_t)(k + 2) * 128 + c4);
        float4 wv3 = *(const float4*)(w2 + (size_t)(k + 3) * 128 + c4);
#pragma unroll
        for (int r = 0; r < 8; r++) {
            float4 a = *(const float4*)&Hs[(r0 + r) * 128 + k];
            acc[r][0] = fmaf(a.x, w0.x, acc[r][0]); acc[r][1] = fmaf(a.x, w0.y, acc[r][1]);
            acc[r][2] = fmaf(a.x, w0.z, acc[r][2]); acc[r][3] = fmaf(a.x, w0.w, acc[r][3]);
            acc[r][0] = fmaf(a.y, wv1.x, acc[r][0]); acc[r][1] = fmaf(a.y, wv1.y, acc[r][1]);
            acc[r][2] = fmaf(a.y, wv1.z, acc[r][2]); acc[r][3] = fmaf(a.y, wv1.w, acc[r][3]);
            acc[r][0] = fmaf(a.z, wv2.x, acc[r][0]); acc[r][1] = fmaf(a.z, wv2.y, acc[r][1]);
            acc[r][2] = fmaf(a.z, wv2.z, acc[r][2]); acc[r][3] = fmaf(a.z, wv2.w, acc[r][3]);
            acc[r][0] = fmaf(a.w, wv3.x, acc[r][0]); acc[r][1] = fmaf(a.w, wv3.y, acc[r][1]);
            acc[r][2] = fmaf(a.w, wv3.z, acc[r][2]); acc[r][3] = fmaf(a.w, wv3.w, acc[r][3]);
        }
    }
    for (int k = 0; k < 32; k += 4) {
        float4 w0 = *(const float4*)(cw + (size_t)(k + 0) * 128 + c4);
        float4 wv1 = *(const float4*)(cw + (size_t)(k + 1) * 128 + c4);
        float4 wv2 = *(const float4*)(cw + (size_t)(k + 2) * 128 + c4);
        float4 wv3 = *(const float4*)(cw + (size_t)(k + 3) * 128 + c4);
#pragma unroll
        for (int r = 0; r < 8; r++) {
            float4 a = *(const float4*)&Cs[(r0 + r) * 32 + k];
            acc[r][0] = fmaf(a.x, w0.x, acc[r][0]); acc[r][1] = fmaf(a.x, w0.y, acc[r][1]);
            acc[r][2] = fmaf(a.x, w0.z, acc[r][2]); acc[r][3] = fmaf(a.x, w0.w, acc[r][3]);
            acc[r][0] = fmaf(a.y, wv1.x, acc[r][0]); acc[r][1] = fmaf(a.y, wv1.y, acc[r][1]);
            acc[r][2] = fmaf(a.y, wv1.z, acc[r][2]); acc[r][3] = fmaf(a.y, wv1.w, acc[r][3]);
            acc[r][0] = fmaf(a.z, wv2.x, acc[r][0]); acc[r][1] = fmaf(a.z, wv2.y, acc[r][1]);
            acc[r][2] = fmaf(a.z, wv2.z, acc[r][2]); acc[r][3] = fmaf(a.z, wv2.w, acc[r][3]);
            acc[r][0] = fmaf(a.w, wv3.x, acc[r][0]); acc[r][1] = fmaf(a.w, wv3.y, acc[r][1]);
            acc[r][2] = fmaf(a.w, wv3.z, acc[r][2]); acc[r][3] = fmaf(a.w, wv3.w, acc[r][3]);
        }
    }
#pragma unroll
    for (int r = 0; r < 8; r++) {
        const int row = r0 + r;
        const int sc = c4 ^ ((row & 7) << 2);
        *(float4*)&HG[row * 128 + sc] = make_float4(acc[r][0], acc[r][1], acc[r][2], acc[r][3]);
    }
    __syncthreads();

    if (t < 64) {
        const int row = R0 + t;
        const int sw = (t & 7) << 2;

        float mu[16], lv[16];
#pragma unroll
        for (int j = 0; j < 16; j++) { mu[j] = mub[j]; lv[j] = lvb[j]; }
        for (int kq = 0; kq < 32; kq++) {
            float4 h = *(const float4*)&HG[t * 128 + ((kq * 4) ^ sw)];
            float hh[4] = { h.x, h.y, h.z, h.w };
#pragma unroll
            for (int u = 0; u < 4; u++) {
                const int k = kq * 4 + u;
                const float* mr = muw + k * 16;
                const float* lr = lvw + k * 16;
#pragma unroll
                for (int j = 0; j < 16; j++) {
                    mu[j] = fmaf(hh[u], mr[j], mu[j]);
                    lv[j] = fmaf(hh[u], lr[j], lv[j]);
                }
            }
        }

        // prior from ctx (global read, coalesced 32 floats/lane)
        float cx[32];
        {
            const float4* cr4 = (const float4*)(ctx + (size_t)row * 32);
#pragma unroll
            for (int i = 0; i < 8; i++) {
                float4 v = cr4[i];
                cx[i * 4 + 0] = v.x; cx[i * 4 + 1] = v.y; cx[i * 4 + 2] = v.z; cx[i * 4 + 3] = v.w;
            }
        }
        float pmu[16], plv[16];
#pragma unroll
        for (int j = 0; j < 16; j++) { pmu[j] = pmb[j]; plv[j] = plb[j]; }
#pragma unroll 4
        for (int k = 0; k < 32; k++) {
            const float* mr = pmw + k * 16;
            const float* lr = plw + k * 16;
#pragma unroll
            for (int j = 0; j < 16; j++) {
                pmu[j] = fmaf(cx[k], mr[j], pmu[j]);
                plv[j] = fmaf(cx[k], lr[j], plv[j]);
            }
        }

        float e[16];
        {
            const float4* er = (const float4*)(eps + (size_t)row * 16);
#pragma unroll
            for (int i = 0; i < 4; i++) {
                float4 v = er[i];
                e[i * 4 + 0] = v.x; e[i * 4 + 1] = v.y; e[i * 4 + 2] = v.z; e[i * 4 + 3] = v.w;
            }
        }
        float z[16];
        float klp = 0.f;
#pragma unroll
        for (int j = 0; j < 16; j++) {
            float m = mu[j], l = lv[j];
            z[j] = fmaf(e[j], expf(0.5f * l), m);
            float dm = m - pmu[j];
            klp += plv[j] - l + (expf(l) + dm * dm) / expf(plv[j]) - 1.f;
        }

        float best = 3.4e38f; int bi = 0;
        for (int c = 0; c < 32; c++) {
            const float* cr = cbg + c * 16;
            float dot = 0.f, nrm = 0.f;
#pragma unroll
            for (int j = 0; j < 16; j++) { float cv = cr[j]; dot = fmaf(z[j], cv, dot); nrm = fmaf(cv, cv, nrm); }
            float d = nrm - 2.f * dot;
            if (d < best) { best = d; bi = c; }
        }
        const float4* cq = (const float4*)(cbg + bi * 16);
        float vqp = 0.f;
        float zg[16];
#pragma unroll
        for (int i = 0; i < 4; i++) {
            float4 q = cq[i];
            float qq[4] = { q.x, q.y, q.z, q.w };
#pragma unroll
            for (int jj = 0; jj < 4; jj++) {
                int j = i * 4 + jj;
                float diff = qq[jj] - z[j];
                vqp += diff * diff;
                zg[j] = z[j] + diff;
            }
        }

        {
            float4* o_zg = (float4*)(out + (size_t)2 * NELEM + (size_t)row * 16);
            float4* o_zc = (float4*)(out + (size_t)3 * NELEM + (size_t)row * 16);
#pragma unroll
            for (int i = 0; i < 4; i++) {
                o_zg[i] = make_float4(zg[i * 4], zg[i * 4 + 1], zg[i * 4 + 2], zg[i * 4 + 3]);
                o_zc[i] = make_float4(z[i * 4], z[i * 4 + 1], z[i * 4 + 2], z[i * 4 + 3]);
            }
        }

#pragma unroll
        for (int m = 32; m >= 1; m >>= 1) { klp += __shfl_xor(klp, m); vqp += __shfl_xor(vqp, m); }
        if (t == 0) {
            g_p3[blockIdx.x * 2 + 0] = klp;
            g_p3[blockIdx.x * 2 + 1] = vqp;
        }
    }
}

// ---------------------------------------------------------------------------
// K4: final deterministic reduction over 1024 block-partials
// ---------------------------------------------------------------------------
__global__ __launch_bounds__(256) void k4_finalize(float* __restrict__ out)
{
    const int t = threadIdx.x;
    float kli = 0.f, vqi = 0.f, klg = 0.f, vqg = 0.f;
#pragma unroll
    for (int i = 0; i < 4; i++) {
        const int id = i * 256 + t;
        kli += g_p2[id * 2 + 0]; vqi += g_p2[id * 2 + 1];
        klg += g_p3[id * 2 + 0]; vqg += g_p3[id * 2 + 1];
    }
#pragma unroll
    for (int m = 32; m >= 1; m >>= 1) {
        kli += __shfl_xor(kli, m); vqi += __shfl_xor(vqi, m);
        klg += __shfl_xor(klg, m); vqg += __shfl_xor(vqg, m);
    }
    __shared__ float red[4][4];
    const int wv = t >> 6, ln = t & 63;
    if (ln == 0) { red[wv][0] = kli; red[wv][1] = vqi; red[wv][2] = klg; red[wv][3] = vqg; }
    __syncthreads();
    if (t == 0) {
        float a = 0.f, bq = 0.f, c = 0.f, d = 0.f;
#pragma unroll
        for (int w = 0; w < 4; w++) { a += red[w][0]; bq += red[w][1]; c += red[w][2]; d += red[w][3]; }
        const float invN = 1.f / (float)NELEM;
        float kl_i = -0.5f * a * invN;
        float vq_i = 0.5f * bq * invN;   // 0.25 * (commit + code) = 0.5 * mse
        float kl_g = 0.5f * c * invN;
        float vq_g = 0.5f * d * invN;
        out[(size_t)4 * NELEM + 0] = 2.0f * (kl_i + kl_g) + vq_i + vq_g;
        out[(size_t)4 * NELEM + 1] = kl_i;
        out[(size_t)4 * NELEM + 2] = kl_g;
    }
}

extern "C" void kernel_launch(void* const* d_in, const int* in_sizes, int n_in,
                              void* d_out, int out_size, void* d_ws, size_t ws_size,
                              hipStream_t stream)
{
    (void)in_sizes; (void)n_in; (void)out_size; (void)d_ws; (void)ws_size;
    const float* ind     = (const float*)d_in[0];
    const float* grp     = (const float*)d_in[1];
    const float* ctx     = (const float*)d_in[2];
    const float* eps_i   = (const float*)d_in[3];
    const float* eps_g   = (const float*)d_in[4];
    const float* ei_w1   = (const float*)d_in[5];
    const float* ei_b1   = (const float*)d_in[6];
    const float* ei_w2   = (const float*)d_in[7];
    const float* ei_b2   = (const float*)d_in[8];
    const float* ei_mu_w = (const float*)d_in[9];
    const float* ei_mu_b = (const float*)d_in[10];
    const float* ei_lv_w = (const float*)d_in[11];
    const float* ei_lv_b = (const float*)d_in[12];
    const float* cb_i    = (const float*)d_in[13];
    const float* eg_w1   = (const float*)d_in[14];
    const float* eg_b1   = (const float*)d_in[15];
    const float* eg_w2   = (const float*)d_in[16];
    const float* eg_b2   = (const float*)d_in[17];
    const float* eg_ctxw = (const float*)d_in[18];
    const float* eg_ctxb = (const float*)d_in[19];
    const float* eg_mu_w = (const float*)d_in[20];
    const float* eg_mu_b = (const float*)d_in[21];
    const float* eg_lv_w = (const float*)d_in[22];
    const float* eg_lv_b = (const float*)d_in[23];
    const float* cb_g    = (const float*)d_in[24];
    const float* pr_mu_w = (const float*)d_in[25];
    const float* pr_mu_b = (const float*)d_in[26];
    const float* pr_lv_w = (const float*)d_in[27];
    const float* pr_lv_b = (const float*)d_in[28];
    float* out = (float*)d_out;

    k1_group_stage1<<<16384, 256, 0, stream>>>(grp, eg_w1, eg_b1);
    k2_individual<<<1024, 256, 0, stream>>>(ind, eps_i, ei_w1, ei_b1, ei_w2, ei_b2,
                                            ei_mu_w, ei_mu_b, ei_lv_w, ei_lv_b, cb_i, out);
    k3_group_stage2<<<1024, 256, 0, stream>>>(ctx, eps_g, eg_w2, eg_b2, eg_ctxw, eg_ctxb,
                                              eg_mu_w, eg_mu_b, eg_lv_w, eg_lv_b, cb_g,
                                              pr_mu_w, pr_mu_b, pr_lv_w, pr_lv_b, out);
    k4_finalize<<<1, 256, 0, stream>>>(out);
}